// Round 10
// baseline (4334.352 us; speedup 1.0000x reference)
//
#include <hip/hip_runtime.h>
#include <stdint.h>

// R14: R13 (3636 us) + coalesced exchange layout + barrier-free auto steps.
// R13 ledger: 8.5k cy/step = busy 2.3k + stall 6.2k; WRITE 1.09GB vs 530MB
// logical => 2x publish write-amplification; consumer 48 scattered dword UC
// loads/thread. Changes:
//  (1) exchange row-pair-major [p][col]: publisher 2 contiguous u32/lane
//      (full 64B lines); consumer 2 consecutive u64 UC loads per chunk
//      (12 total, 1 line each) + 4 v_perm_b32 unpack per frag (~24 VALU
//      vs ~96). Values bit-identical.
//  (2) auto: barrier B + feedback-LDS round trip DELETED. All waves compute
//      y redundantly (8 MFMAs; ya is wave-invariant), pack to bf16, and do
//      an intra-wave LDS transpose (4 ds_write_b16 + ds_read_b128, 256B
//      per-wave scratch; same-wave DS pipe is in-order -> no syncthreads).
//      kg=3 lanes build the x-chunk A-frag (k=24..31 = feedback cols) from
//      that scratch. 1 barrier/step everywhere; wave0 straggle gone.
// Decision: >=3.45ms null => residual is the raw UC RT chain => R15 =
// same-XCD L2 exchange (XCC_ID verify + UC fallback).

#define B_TOTAL   1024
#define H_DIM     256
#define F_WARM    32
#define F_AUTO    24
#define O_DIM     8
#define T_WARM    512
#define T_TOTAL   1024
#define N4H       1024
#define A_STR     104   // x(32)+h(64)+pad(8): 208 B/row, 16B-aligned

typedef __attribute__((ext_vector_type(8))) short short8;
typedef __attribute__((ext_vector_type(4))) float float4v;

#define GLOBAL_AS __attribute__((address_space(1)))
#define LDS_AS    __attribute__((address_space(3)))
#define XSCOPE    __HIP_MEMORY_SCOPE_AGENT

__device__ __forceinline__ short f2bf(float x) {
    union { float f; uint32_t u; } v; v.f = x;
    uint32_t r = v.u + 0x7FFFu + ((v.u >> 16) & 1u);   // RNE
    return (short)(r >> 16);
}
__device__ __forceinline__ float sigmoid_(float x) {
    const float e = __expf(-x);
    return __builtin_amdgcn_rcpf(1.0f + e);
}
__device__ __forceinline__ float tanh_(float x) {
    const float e = __expf(-2.0f * fabsf(x));
    const float t = (1.0f - e) * __builtin_amdgcn_rcpf(1.0f + e);
    return x >= 0.0f ? t : -t;
}
__device__ __forceinline__ uint32_t uc_ld(const uint32_t* p) {
    return __hip_atomic_load(p, __ATOMIC_RELAXED, XSCOPE);
}
__device__ __forceinline__ void uc_st(uint32_t* p, uint32_t v) {
    __hip_atomic_store(p, v, __ATOMIC_RELAXED, XSCOPE);
}
// Load one A-frag (row n16, cols lc*32+kg*8..+7) from a row-pair-major slice.
__device__ __forceinline__ short8 ld_slice(const uint32_t* pd, int lc, int kg,
                                           int n16, uint32_t psel) {
    const uint64_t* p64 =
        (const uint64_t*)(pd + (n16 >> 1) * 64 + lc * 32 + kg * 8);
    union { uint32_t d[4]; short8 s; } u;
    #pragma unroll
    for (int j = 0; j < 4; ++j) {
        const uint64_t wv = __hip_atomic_load(p64 + j, __ATOMIC_RELAXED, XSCOPE);
        u.d[j] = __builtin_amdgcn_perm((uint32_t)(wv >> 32), (uint32_t)wv, psel);
    }
    return u.s;
}

__global__ __launch_bounds__(256, 1)
void lstm_q4(const float* __restrict__ c0, const float* __restrict__ h0,
             const float* __restrict__ warm, const float* __restrict__ autoin,
             const float* __restrict__ W_ih, const float* __restrict__ W_hh,
             const float* __restrict__ bvec, const float* __restrict__ W_out,
             const float* __restrict__ b_out, float* __restrict__ out,
             unsigned short* __restrict__ ws)
{
    const int tid  = threadIdx.x;
    const int w    = tid >> 6;        // wave 0..3 -> own h-units [q*64+w*16,+16)
    const int l    = tid & 63;
    const int n16  = l & 15;          // MFMA n / A row (m)
    const int kg   = l >> 4;          // k-group 0..3
    const int bid  = blockIdx.x;
    const int tile = bid & 63;        // batch tile
    const int q    = bid >> 6;        // h-quarter 0..3
    const int row0 = tile * 16;
    const int hcol = q * 64 + w * 16 + n16;   // own global h col
    const int cl   = w * 16 + n16;            // own local col (0..63)
    const uint32_t psel = 0x05040100u + ((n16 & 1) ? 0x02020202u : 0u);

    const int pb0 = ((q + 1) & 3) * 64 + tile;
    const int pb1 = ((q + 2) & 3) * 64 + tile;
    const int pb2 = ((q + 3) & 3) * 64 + tile;

    uint32_t* myflag = (uint32_t*)((char*)ws + (size_t)bid * 64);
    const uint32_t* pf0 = (const uint32_t*)((char*)ws + (size_t)pb0 * 64);
    const uint32_t* pf1 = (const uint32_t*)((char*)ws + (size_t)pb1 * 64);
    const uint32_t* pf2 = (const uint32_t*)((char*)ws + (size_t)pb2 * 64);
    uint32_t* xbase = (uint32_t*)((char*)ws + 16384);
    uint32_t*       obuf = xbase + (size_t)bid * 1024;   // 2 parity x 512 u32
    const uint32_t* pd0  = xbase + (size_t)pb0 * 1024;
    const uint32_t* pd1  = xbase + (size_t)pb1 * 1024;
    const uint32_t* pd2  = xbase + (size_t)pb2 * 1024;

    __shared__ __align__(16) short Abuf[2][16 * A_STR]; // [x(32) | own h(64) | pad]
    __shared__ __align__(16) unsigned short wsWl[4096]; // W_out MFMA B-frags (K=256)
    __shared__ float biasL[256];                        // own 4 gates x 64
    __shared__ __align__(16) float xstage[512];         // x_{t+1} prefetch
    __shared__ __align__(16) short ylds[4][128];        // per-wave y transpose

    // ---- W_out frags -> LDS ----
    for (int idx = tid; idx < 4096; idx += 256) {
        const int i = idx & 7, lane = (idx >> 3) & 63, kk = idx >> 9;
        const int k = kk * 32 + (lane >> 4) * 8 + i;
        const int n = lane & 15;
        wsWl[idx] = (unsigned short)((n < O_DIM) ? f2bf(W_out[k * O_DIM + n]) : (short)0);
    }
    // ---- bias: own 256 cols, layout [g][64] ----
    {
        const int g = tid >> 6, loc = tid & 63;
        biasL[tid] = bvec[g * 256 + q * 64 + loc];
    }

    // ---- register weights: 36 frags = 144 regs (compile-time indexed) ----
    short8 bwx[4];          // x chunk (W_ih rows 0..31), own cols
    short8 bwo[2][4];       // own h chunks lc=0,1
    short8 bwhp[3][2][4];   // partner chunks, partner-relative order
    #pragma unroll
    for (int g = 0; g < 4; ++g) {
        const int col = g * 256 + hcol;
        {
            short8 f;
            #pragma unroll
            for (int i = 0; i < 8; ++i)
                f[i] = f2bf(W_ih[(kg * 8 + i) * N4H + col]);
            bwx[g] = f;
        }
        #pragma unroll
        for (int lc = 0; lc < 2; ++lc) {
            short8 f;
            #pragma unroll
            for (int i = 0; i < 8; ++i)
                f[i] = f2bf(W_hh[(q * 64 + lc * 32 + kg * 8 + i) * N4H + col]);
            bwo[lc][g] = f;
        }
        #pragma unroll
        for (int pi = 0; pi < 3; ++pi) {
            const int qq = (q + 1 + pi) & 3;
            #pragma unroll
            for (int lc = 0; lc < 2; ++lc) {
                short8 f;
                #pragma unroll
                for (int i = 0; i < 8; ++i)
                    f[i] = f2bf(W_hh[(qq * 64 + lc * 32 + kg * 8 + i) * N4H + col]);
                bwhp[pi][lc][g] = f;
            }
        }
    }

    const float bout = (n16 < O_DIM) ? b_out[n16] : 0.0f;   // all waves (auto y)

    // ---- c state: rows kg*4+r, own col hcol ----
    float creg[4];
    #pragma unroll
    for (int r = 0; r < 4; ++r)
        creg[r] = c0[(size_t)(row0 + kg * 4 + r) * H_DIM + hcol];

    // ---- initial A (buf 0): x_0 + own h0 slice ----
    #pragma unroll
    for (int e = 0; e < 2; ++e) {
        const int idx = tid + e * 256;
        const int r = idx >> 5, cx = idx & 31;
        Abuf[0][r * A_STR + cx] =
            f2bf(warm[(size_t)(row0 + r) * (T_WARM * F_WARM) + cx]);   // t=0
    }
    #pragma unroll
    for (int e = 0; e < 4; ++e) {
        const int idx = tid + e * 256;
        const int r = idx >> 6, c = idx & 63;
        Abuf[0][r * A_STR + F_WARM + c] =
            f2bf(h0[(size_t)(row0 + r) * H_DIM + q * 64 + c]);
    }
    // ---- phf init: partner h0 frags (6 chunks) ----
    short8 phf[3][2];
    #pragma unroll
    for (int pi = 0; pi < 3; ++pi) {
        const int qq = (q + 1 + pi) & 3;
        #pragma unroll
        for (int lc = 0; lc < 2; ++lc) {
            short8 f;
            #pragma unroll
            for (int i = 0; i < 8; ++i)
                f[i] = f2bf(h0[(size_t)(row0 + n16) * H_DIM
                               + qq * 64 + lc * 32 + kg * 8 + i]);
            phf[pi][lc] = f;
        }
    }

    __syncthreads();                            // prologue LDS published
    float bb[4];
    #pragma unroll
    for (int g = 0; g < 4; ++g) bb[g] = biasL[g * 64 + cl];

    const int aoff = n16 * A_STR + kg * 8;
    short* curp = &Abuf[0][0];
    short* nxtp = &Abuf[1][0];
    const short8* wsW8 = (const short8*)wsWl;

    for (int t = 0; t < T_TOTAL; ++t) {
        __syncthreads();                        // A_t: buf + publish-acks drained

        if (tid == 0)                           // h_{t-1} readable
            uc_st(myflag, (uint32_t)t);

        // ---- pre-issue partner flag loads (covered by own MFMAs) ----
        uint32_t fv0 = 0, fv1 = 0, fv2 = 0;
        if (t >= 1) { fv0 = uc_ld(pf0); fv1 = uc_ld(pf1); fv2 = uc_ld(pf2); }

        // ---- async prefetch x_{t+1} -> xstage ----
        const int tn = t + 1;
        if (tn < T_TOTAL) {
            #pragma unroll
            for (int e = 0; e < 2; ++e) {
                const int idx = tid + e * 256;
                const int r = idx >> 5, cx = idx & 31;
                const float* gp;
                if (tn < T_WARM)
                    gp = &warm[(size_t)(row0 + r) * (T_WARM * F_WARM)
                               + (size_t)tn * F_WARM + cx];
                else
                    gp = &autoin[(size_t)(row0 + r) * (T_WARM * F_AUTO)
                                 + (size_t)(tn - T_WARM) * F_AUTO
                                 + ((cx < F_AUTO) ? cx : 0)];
                __builtin_amdgcn_global_load_lds(
                    (const GLOBAL_AS void*)gp,
                    (LDS_AS void*)&xstage[e * 256 + w * 64], 4, 0, 0);
            }
        }

        // ---- own A-frags + own-chunk MFMAs (8) ----
        const short* ab = curp + aoff;
        short8 afh[2];
        #pragma unroll
        for (int lc = 0; lc < 2; ++lc)
            afh[lc] = *(const short8*)(ab + 32 + lc * 32);

        float4v acc[4];
        #pragma unroll
        for (int g = 0; g < 4; ++g)
            acc[g] = (float4v){0.f, 0.f, 0.f, 0.f};
        #pragma unroll
        for (int lc = 0; lc < 2; ++lc)
            #pragma unroll
            for (int g = 0; g < 4; ++g)
                acc[g] = __builtin_amdgcn_mfma_f32_16x16x32_bf16(
                             afh[lc], bwo[lc][g], acc[g], 0, 0, 0);

        // ---- warm: x-chunk MFMA early (no feedback dep; covers data RT) ----
        if (t < T_WARM) {
            const short8 af = *(const short8*)(ab);
            #pragma unroll
            for (int g = 0; g < 4; ++g)
                acc[g] = __builtin_amdgcn_mfma_f32_16x16x32_bf16(
                             af, bwx[g], acc[g], 0, 0, 0);
        }

        // ---- confirm flags, then load partner slices (coalesced u64) ----
        if (t >= 1) {
            const uint32_t want = (uint32_t)t;
            while (fv0 < want || fv1 < want || fv2 < want) {
                __builtin_amdgcn_s_sleep(1);
                fv0 = uc_ld(pf0); fv1 = uc_ld(pf1); fv2 = uc_ld(pf2);
            }
            asm volatile("" ::: "memory");
            const int slot = ((t - 1) & 1) * 512;
            #pragma unroll
            for (int pi = 0; pi < 3; ++pi) {
                const uint32_t* pd =
                    ((pi == 0) ? pd0 : (pi == 1) ? pd1 : pd2) + slot;
                #pragma unroll
                for (int lc = 0; lc < 2; ++lc)
                    phf[pi][lc] = ld_slice(pd, lc, kg, n16, psel);
            }
        }

        // ---- partner-chunk MFMAs (24) ----
        #pragma unroll
        for (int pi = 0; pi < 3; ++pi)
            #pragma unroll
            for (int lc = 0; lc < 2; ++lc)
                #pragma unroll
                for (int g = 0; g < 4; ++g)
                    acc[g] = __builtin_amdgcn_mfma_f32_16x16x32_bf16(
                                 phf[pi][lc], bwhp[pi][lc][g], acc[g], 0, 0, 0);

        // ---- y_{t-1}: warm = q0/w0 only (out); auto = ALL waves (feedback) ----
        if (t >= 1 && (t >= T_WARM || (q == 0 && w == 0))) {
            if (t >= T_WARM || (q == 0 && w == 0)) {
                float4v ya = (float4v){bout, bout, bout, bout};
                #pragma unroll
                for (int lc = 0; lc < 2; ++lc)
                    ya = __builtin_amdgcn_mfma_f32_16x16x32_bf16(
                             afh[lc], wsW8[(q * 2 + lc) * 64 + l], ya, 0, 0, 0);
                #pragma unroll
                for (int pi = 0; pi < 3; ++pi) {
                    const int qq = (q + 1 + pi) & 3;
                    #pragma unroll
                    for (int lc = 0; lc < 2; ++lc)
                        ya = __builtin_amdgcn_mfma_f32_16x16x32_bf16(
                                 phf[pi][lc], wsW8[(qq * 2 + lc) * 64 + l], ya, 0, 0, 0);
                }
                if (q == 0 && w == 0 && n16 < O_DIM) {
                    #pragma unroll
                    for (int r = 0; r < 4; ++r)
                        out[(size_t)(row0 + kg * 4 + r) * (T_TOTAL * O_DIM)
                            + (size_t)(t - 1) * O_DIM + n16] = ya[r];
                }
                if (t >= T_WARM) {      // intra-wave y transpose -> ylds[w]
                    uint32_t yp0, yp1;
                    asm("v_cvt_pk_bf16_f32 %0, %1, %2" : "=v"(yp0) : "v"(ya[0]), "v"(ya[1]));
                    asm("v_cvt_pk_bf16_f32 %0, %1, %2" : "=v"(yp1) : "v"(ya[2]), "v"(ya[3]));
                    if (n16 < O_DIM) {
                        short* yl = &ylds[w][0];
                        yl[(kg * 4 + 0) * 8 + n16] = (short)(yp0 & 0xFFFF);
                        yl[(kg * 4 + 1) * 8 + n16] = (short)(yp0 >> 16);
                        yl[(kg * 4 + 2) * 8 + n16] = (short)(yp1 & 0xFFFF);
                        yl[(kg * 4 + 3) * 8 + n16] = (short)(yp1 >> 16);
                    }
                    __builtin_amdgcn_wave_barrier();    // order DS write->read
                }
            }
        }

        // ---- auto: x-chunk MFMA (kg=3 sources feedback from ylds) ----
        if (t >= T_WARM) {
            short8 af;
            if (kg == 3) af = *(const short8*)&ylds[w][n16 * 8];
            else         af = *(const short8*)(ab);
            #pragma unroll
            for (int g = 0; g < 4; ++g)
                acc[g] = __builtin_amdgcn_mfma_f32_16x16x32_bf16(
                             af, bwx[g], acc[g], 0, 0, 0);
        }

        // ---- gates + c/h update (4 h-vals/thread); HW bf16 pack ----
        uint32_t hp[2];
        {
            float hv0, hv1, hv2, hv3;
            #pragma unroll
            for (int r = 0; r < 4; ++r) {
                const float ig = sigmoid_(acc[0][r] + bb[0]);
                const float fg = sigmoid_(acc[1][r] + bb[1]);
                const float gg = tanh_(acc[2][r] + bb[2]);
                const float og = sigmoid_(acc[3][r] + bb[3]);
                const float cc = fg * creg[r] + ig * gg;
                creg[r] = cc;
                const float hh = og * tanh_(cc);
                if (r == 0) hv0 = hh; else if (r == 1) hv1 = hh;
                else if (r == 2) hv2 = hh; else hv3 = hh;
            }
            uint32_t u0, u1;
            asm("v_cvt_pk_bf16_f32 %0, %1, %2" : "=v"(u0) : "v"(hv0), "v"(hv1));
            asm("v_cvt_pk_bf16_f32 %0, %1, %2" : "=v"(u1) : "v"(hv2), "v"(hv3));
            hp[0] = u0; hp[1] = u1;
        }

        // ---- drain x-prefetch loads (cheap) before issuing UC publishes ----
        asm volatile("s_waitcnt vmcnt(0)" ::: "memory");

        // ---- commit prefetched x_{t+1} into NEXT buffer ----
        if (tn < T_TOTAL) {
            #pragma unroll
            for (int e = 0; e < 2; ++e) {
                const int idx = tid + e * 256;
                const int r = idx >> 5, cx = idx & 31;
                if (tn < T_WARM || cx < F_AUTO)
                    nxtp[r * A_STR + cx] = f2bf(xstage[idx]);
            }
        }

        // ---- publish own h_t slice: row-pair-major, fully coalesced ----
        {
            uint32_t* ob = obuf + (t & 1) * 512;
            uc_st(&ob[(kg * 2 + 0) * 64 + cl], hp[0]);
            uc_st(&ob[(kg * 2 + 1) * 64 + cl], hp[1]);
        }

        // ---- write own h_t into NEXT buffer ----
        {
            const int ac = F_WARM + cl;
            nxtp[(kg * 4 + 0) * A_STR + ac] = (short)(hp[0] & 0xFFFF);
            nxtp[(kg * 4 + 1) * A_STR + ac] = (short)(hp[0] >> 16);
            nxtp[(kg * 4 + 2) * A_STR + ac] = (short)(hp[1] & 0xFFFF);
            nxtp[(kg * 4 + 3) * A_STR + ac] = (short)(hp[1] >> 16);
        }

        { short* tswap = curp; curp = nxtp; nxtp = tswap; }
        // loop-top barrier A_{t+1} drains publishes; buf[(t+1)&1] ready
    }

    // ---- epilogue: y_{T-1} (q0 wave0; needs partner h_{T-1}) ----
    __syncthreads();                            // drains final publishes
    if (tid == 0)
        uc_st(myflag, (uint32_t)T_TOTAL);
    if (q == 0 && w == 0) {
        const uint32_t want = (uint32_t)T_TOTAL;
        uint32_t fv0 = uc_ld(pf0), fv1 = uc_ld(pf1), fv2 = uc_ld(pf2);
        while (fv0 < want || fv1 < want || fv2 < want) {
            __builtin_amdgcn_s_sleep(1);
            fv0 = uc_ld(pf0); fv1 = uc_ld(pf1); fv2 = uc_ld(pf2);
        }
        asm volatile("" ::: "memory");
        const int slot = ((T_TOTAL - 1) & 1) * 512;
        #pragma unroll
        for (int pi = 0; pi < 3; ++pi) {
            const uint32_t* pd = ((pi == 0) ? pd0 : (pi == 1) ? pd1 : pd2) + slot;
            #pragma unroll
            for (int lc = 0; lc < 2; ++lc)
                phf[pi][lc] = ld_slice(pd, lc, kg, n16, psel);
        }
        const short* ab = curp + aoff;          // curp holds h_{T-1}
        float4v ya = (float4v){bout, bout, bout, bout};
        #pragma unroll
        for (int lc = 0; lc < 2; ++lc)
            ya = __builtin_amdgcn_mfma_f32_16x16x32_bf16(
                     *(const short8*)(ab + 32 + lc * 32),
                     wsW8[(0 * 2 + lc) * 64 + l], ya, 0, 0, 0);
        #pragma unroll
        for (int pi = 0; pi < 3; ++pi) {
            const int qq = (0 + 1 + pi) & 3;
            #pragma unroll
            for (int lc = 0; lc < 2; ++lc)
                ya = __builtin_amdgcn_mfma_f32_16x16x32_bf16(
                         phf[pi][lc], wsW8[(qq * 2 + lc) * 64 + l], ya, 0, 0, 0);
        }
        if (n16 < O_DIM) {
            #pragma unroll
            for (int r = 0; r < 4; ++r)
                out[(size_t)(row0 + kg * 4 + r) * (T_TOTAL * O_DIM)
                    + (size_t)(T_TOTAL - 1) * O_DIM + n16] = ya[r];
        }
    }
}

extern "C" void kernel_launch(void* const* d_in, const int* in_sizes, int n_in,
                              void* d_out, int out_size, void* d_ws, size_t ws_size,
                              hipStream_t stream) {
    (void)in_sizes; (void)n_in; (void)out_size; (void)ws_size;
    const float* c0   = (const float*)d_in[0];
    const float* h0   = (const float*)d_in[1];
    const float* warm = (const float*)d_in[2];
    const float* aut  = (const float*)d_in[3];
    const float* Wih  = (const float*)d_in[4];
    const float* Whh  = (const float*)d_in[5];
    const float* b    = (const float*)d_in[6];
    const float* Wout = (const float*)d_in[7];
    const float* bout = (const float*)d_in[8];
    float* out = (float*)d_out;
    unsigned short* ws = (unsigned short*)d_ws;
    // ws layout: [0,16KB) flags (64B/WG); [16KB,16KB+1MB) h-slices:
    //            per WG 2 parity x 2KB, row-pair-major [p][col] u32.
    hipMemsetAsync(d_ws, 0, 16384, stream);
    hipLaunchKernelGGL(lstm_q4, dim3(256), dim3(256), 0, stream,
                       c0, h0, warm, aut, Wih, Whh, b, Wout, bout, out, ws);
}